// Round 12
// baseline (42.008 us; speedup 1.0000x reference)
//
#include <hip/hip_runtime.h>
#include <hip/hip_bf16.h>

typedef float f32x4 __attribute__((ext_vector_type(4)));
typedef short bf16x8 __attribute__((ext_vector_type(8)));

// pack 2 fp32 -> 2 bf16 (RNE): bits[15:0]=bf16(a), bits[31:16]=bf16(b)
__device__ inline unsigned cvt_pk_bf16(float a, float b) {
    unsigned r;
    asm("v_cvt_pk_bf16_f32 %0, %1, %2" : "=v"(r) : "v"(a), "v"(b));
    return r;
}
union FragU { unsigned u[4]; bf16x8 v; };

__device__ inline bf16x8 pack8(const float f[8]) {
    FragU x;
    x.u[0] = cvt_pk_bf16(f[0], f[1]);
    x.u[1] = cvt_pk_bf16(f[2], f[3]);
    x.u[2] = cvt_pk_bf16(f[4], f[5]);
    x.u[3] = cvt_pk_bf16(f[6], f[7]);
    return x.v;
}

__device__ inline bf16x8 splat8(float v) {
    FragU x;
    unsigned p = cvt_pk_bf16(v, v);
    x.u[0] = p; x.u[1] = p; x.u[2] = p; x.u[3] = p;
    return x.v;
}

// B-operand for one 64x8 G (flat [k][s], k=r*8+d), exact bf16 hi+lo split.
// Slot (q,grp,e) holds G[32q+8grp+e][col]; cols >= 8 zero padding.
__device__ inline void build_b(const float* __restrict__ G, int col, int grp,
                               bf16x8* Bh, bf16x8* Bl) {
    #pragma unroll
    for (int q = 0; q < 2; ++q) {
        FragU hi, lo;
        #pragma unroll
        for (int pr = 0; pr < 4; ++pr) {
            float v0 = 0.f, v1 = 0.f;
            if (col < 8) {
                v0 = G[(32*q + 8*grp + 2*pr    ) * 8 + col];
                v1 = G[(32*q + 8*grp + 2*pr + 1) * 8 + col];
            }
            float h0 = __bfloat162float(__float2bfloat16(v0));
            float h1 = __bfloat162float(__float2bfloat16(v1));
            hi.u[pr] = cvt_pk_bf16(h0, h1);
            lo.u[pr] = cvt_pk_bf16(v0 - h0, v1 - h1);
        }
        Bh[q] = hi.v;
        Bl[q] = lo.v;
    }
}

#define POWERS(p, xx)                                              \
    p[0] = 1.f;  p[1] = (xx);      p[2] = p[1]*p[1];               \
    p[3] = p[2]*p[1]; p[4] = p[2]*p[2]; p[5] = p[4]*p[1];          \
    p[6] = p[4]*p[2]; p[7] = p[4]*p[3];

#define ROWW 12   // floats per sample row: vals[0..7], x1, x2, pad (48B, 16B-aligned)

__global__ __launch_bounds__(256) void tt_poly_kernel(
    const float* __restrict__ X,
    const float* __restrict__ G0,   // [d1][r]
    const float* __restrict__ G1,   // [r][d1][s] -> flat [64][8]
    const float* __restrict__ G2,   // [r][d1][s] -> flat [64][8]
    const float* __restrict__ G3,   // [t][d1]
    float* __restrict__ out,
    int B, int NW)                  // NW = total waves in grid
{
    // per-wave buffers: T0=t(+x1,x2), T1=t1, T2=t2, each [64 samples][ROWW]
    __shared__ float L[4][3][64 * ROWW];

    const int tid  = threadIdx.x;
    const int w    = tid >> 6;
    const int lane = tid & 63;
    const int col  = lane & 15;
    const int grp  = lane >> 4;

    // ---- C-layout self-calibration (assumption-free; exact in bf16) ----
    // probe1: A=sample-label, B=ones -> acc[j] = 32*sampleLbl of slot j
    // probe2: A=ones, B=s-label     -> acc[j] = 32*sLbl of slot j
    int rowLbl[4], colLbl[4];
    {
        bf16x8 ones = splat8(1.f);
        bf16x8 lbl  = splat8((float)col);
        f32x4 pr = {0.f, 0.f, 0.f, 0.f};
        f32x4 pc = {0.f, 0.f, 0.f, 0.f};
        pr = __builtin_amdgcn_mfma_f32_16x16x32_bf16(lbl, ones, pr, 0, 0, 0);
        pc = __builtin_amdgcn_mfma_f32_16x16x32_bf16(ones, lbl, pc, 0, 0, 0);
        #pragma unroll
        for (int j = 0; j < 4; ++j) {
            rowLbl[j] = (int)(pr[j] * 0.03125f + 0.5f);
            colLbl[j] = (int)(pc[j] * 0.03125f + 0.5f);
        }
    }

    bf16x8 B1h[2], B1l[2], B2h[2], B2l[2];
    build_b(G1, col, grp, B1h, B1l);
    build_b(G2, col, grp, B2h, B2l);

    float* T0 = &L[w][0][0];
    float* T1 = &L[w][1][0];
    float* T2 = &L[w][2][0];
    const int gw = blockIdx.x * 4 + w;

    #pragma unroll 1
    for (int it = 0; it < 4; ++it) {
        const int b = (it * NW + gw) * 64 + lane;
        float4 xv = make_float4(0.f, 0.f, 0.f, 0.f);
        if (b < B) xv = reinterpret_cast<const float4*>(X)[b];

        // ---- S1 (fp32 VALU, own sample): t[r] = sum_d x0^d G0[d][r] ----
        {
            float p[8];
            POWERS(p, xv.x)
            f32x4 tlo, thi;
            #pragma unroll
            for (int r = 0; r < 4; ++r) {
                float ta = 0.f, tb = 0.f;
                #pragma unroll
                for (int d = 0; d < 8; ++d) {
                    ta = fmaf(p[d], G0[d*8 + r    ], ta);
                    tb = fmaf(p[d], G0[d*8 + r + 4], tb);
                }
                tlo[r] = ta; thi[r] = tb;
            }
            *reinterpret_cast<f32x4*>(&T0[lane*ROWW    ]) = tlo;
            *reinterpret_cast<f32x4*>(&T0[lane*ROWW + 4]) = thi;
            *reinterpret_cast<float2*>(&T0[lane*ROWW + 8]) = make_float2(xv.y, xv.z);
        }
        __syncthreads();

        // ---- S2 (MFMA): t1 = (t (x) P1) @ G1, all 4 sample-groups ----
        #pragma unroll
        for (int g4 = 0; g4 < 4; ++g4) {
            const int base = (g4*16 + col) * ROWW;
            float ta = T0[base + grp];
            float tb = T0[base + grp + 4];
            float x1 = T0[base + 8];
            float p[8];
            POWERS(p, x1)
            float f0[8], f1[8];
            #pragma unroll
            for (int e = 0; e < 8; ++e) { f0[e] = ta*p[e]; f1[e] = tb*p[e]; }
            bf16x8 a0 = pack8(f0), a1 = pack8(f1);
            f32x4 acc = {0.f, 0.f, 0.f, 0.f};
            acc = __builtin_amdgcn_mfma_f32_16x16x32_bf16(a0, B1h[0], acc, 0, 0, 0);
            acc = __builtin_amdgcn_mfma_f32_16x16x32_bf16(a0, B1l[0], acc, 0, 0, 0);
            acc = __builtin_amdgcn_mfma_f32_16x16x32_bf16(a1, B1h[1], acc, 0, 0, 0);
            acc = __builtin_amdgcn_mfma_f32_16x16x32_bf16(a1, B1l[1], acc, 0, 0, 0);
            #pragma unroll
            for (int j = 0; j < 4; ++j)
                if (colLbl[j] < 8)
                    T1[(g4*16 + rowLbl[j])*ROWW + colLbl[j]] = acc[j];
        }
        __syncthreads();

        // ---- S3 (MFMA): t2 = (t1 (x) P2) @ G2 ----
        #pragma unroll
        for (int g4 = 0; g4 < 4; ++g4) {
            const int base = (g4*16 + col) * ROWW;
            float tc = T1[base + grp];
            float td = T1[base + grp + 4];
            float x2 = T0[base + 9];
            float p[8];
            POWERS(p, x2)
            float f0[8], f1[8];
            #pragma unroll
            for (int e = 0; e < 8; ++e) { f0[e] = tc*p[e]; f1[e] = td*p[e]; }
            bf16x8 a0 = pack8(f0), a1 = pack8(f1);
            f32x4 acc = {0.f, 0.f, 0.f, 0.f};
            acc = __builtin_amdgcn_mfma_f32_16x16x32_bf16(a0, B2h[0], acc, 0, 0, 0);
            acc = __builtin_amdgcn_mfma_f32_16x16x32_bf16(a0, B2l[0], acc, 0, 0, 0);
            acc = __builtin_amdgcn_mfma_f32_16x16x32_bf16(a1, B2h[1], acc, 0, 0, 0);
            acc = __builtin_amdgcn_mfma_f32_16x16x32_bf16(a1, B2l[1], acc, 0, 0, 0);
            #pragma unroll
            for (int j = 0; j < 4; ++j)
                if (colLbl[j] < 8)
                    T2[(g4*16 + rowLbl[j])*ROWW + colLbl[j]] = acc[j];
        }
        __syncthreads();

        // ---- S4 (fp32 VALU, own sample): res = sum_t t2[t] * (G3[t]·P3) ----
        {
            f32x4 u0 = *reinterpret_cast<const f32x4*>(&T2[lane*ROWW    ]);
            f32x4 u1 = *reinterpret_cast<const f32x4*>(&T2[lane*ROWW + 4]);
            float p[8];
            POWERS(p, xv.w)
            float res = 0.f;
            #pragma unroll
            for (int t8 = 0; t8 < 8; ++t8) {
                float wt = G3[t8*8];
                #pragma unroll
                for (int d = 1; d < 8; ++d)
                    wt = fmaf(p[d], G3[t8*8 + d], wt);
                float tv = (t8 < 4) ? u0[t8] : u1[t8 - 4];
                res = fmaf(tv, wt, res);
            }
            if (b < B) out[b] = res;
        }
    }
}

extern "C" void kernel_launch(void* const* d_in, const int* in_sizes, int n_in,
                              void* d_out, int out_size, void* d_ws, size_t ws_size,
                              hipStream_t stream) {
    const float* X  = (const float*)d_in[0];
    const float* G0 = (const float*)d_in[1];
    const float* G1 = (const float*)d_in[2];
    const float* G2 = (const float*)d_in[3];
    const float* G3 = (const float*)d_in[4];
    float* out = (float*)d_out;

    int B = in_sizes[0] / 4;                       // X is [B,4]
    int block = 256;
    int grid = (B + 1023) / 1024;                  // 1024 samples per block
    int NW = grid * 4;                             // total waves
    tt_poly_kernel<<<grid, block, 0, stream>>>(X, G0, G1, G2, G3, out, B, NW);
}

// Round 13
// 40.370 us; speedup vs baseline: 1.0406x; 1.0406x over previous
//
#include <hip/hip_runtime.h>
#include <hip/hip_bf16.h>

typedef float f32x4 __attribute__((ext_vector_type(4)));
typedef short bf16x8 __attribute__((ext_vector_type(8)));

// pack 2 fp32 -> 2 bf16 (RNE)
__device__ inline unsigned cvt_pk_bf16(float a, float b) {
    unsigned r;
    asm("v_cvt_pk_bf16_f32 %0, %1, %2" : "=v"(r) : "v"(a), "v"(b));
    return r;
}
union FragU { unsigned u[4]; bf16x8 v; };

__device__ inline bf16x8 pack8(const float f[8]) {
    FragU x;
    x.u[0] = cvt_pk_bf16(f[0], f[1]);
    x.u[1] = cvt_pk_bf16(f[2], f[3]);
    x.u[2] = cvt_pk_bf16(f[4], f[5]);
    x.u[3] = cvt_pk_bf16(f[6], f[7]);
    return x.v;
}

__device__ inline bf16x8 splat8(float v) {
    FragU x;
    unsigned p = cvt_pk_bf16(v, v);
    x.u[0] = p; x.u[1] = p; x.u[2] = p; x.u[3] = p;
    return x.v;
}

// wave-local LDS ordering: drain DS queue + compiler memory/sched fence
__device__ inline void wave_fence() {
    asm volatile("s_waitcnt lgkmcnt(0)" ::: "memory");
    __builtin_amdgcn_sched_barrier(0);
}

// B-operand for one 64x8 G (flat [k][s], k=r*8+d), exact bf16 hi+lo split.
__device__ inline void build_b(const float* __restrict__ G, int col, int grp,
                               bf16x8* Bh, bf16x8* Bl) {
    #pragma unroll
    for (int q = 0; q < 2; ++q) {
        FragU hi, lo;
        #pragma unroll
        for (int pr = 0; pr < 4; ++pr) {
            float v0 = 0.f, v1 = 0.f;
            if (col < 8) {
                v0 = G[(32*q + 8*grp + 2*pr    ) * 8 + col];
                v1 = G[(32*q + 8*grp + 2*pr + 1) * 8 + col];
            }
            float h0 = __bfloat162float(__float2bfloat16(v0));
            float h1 = __bfloat162float(__float2bfloat16(v1));
            hi.u[pr] = cvt_pk_bf16(h0, h1);
            lo.u[pr] = cvt_pk_bf16(v0 - h0, v1 - h1);
        }
        Bh[q] = hi.v;
        Bl[q] = lo.v;
    }
}

#define POWERS(p, xx)                                              \
    p[0] = 1.f;  p[1] = (xx);      p[2] = p[1]*p[1];               \
    p[3] = p[2]*p[1]; p[4] = p[2]*p[2]; p[5] = p[4]*p[1];          \
    p[6] = p[4]*p[2]; p[7] = p[4]*p[3];

#define ROWW 12   // floats per sample row (48B): 8 slots + x1 + x2 + pad

__global__ __launch_bounds__(256) void tt_poly_kernel(
    const float* __restrict__ X,
    const float* __restrict__ G0,   // [d1][r]
    const float* __restrict__ G1,   // [r][d1][s] -> flat [64][8]
    const float* __restrict__ G2,   // [r][d1][s] -> flat [64][8]
    const float* __restrict__ G3,   // [t][d1]
    float* __restrict__ out,
    int B, int NW)
{
    // per-wave buffers: T0 (t + x1,x2), T1, T2; rows pair-interleaved:
    // slot(v) = 2*(v&3) + (v>>2)  =>  (grp, grp+4) adjacent -> ds_read_b64
    __shared__ float L[4][3][64 * ROWW];

    const int tid  = threadIdx.x;
    const int w    = tid >> 6;
    const int lane = tid & 63;
    const int col  = lane & 15;
    const int grp  = lane >> 4;

    // ---- C-layout self-calibration (assumption-free; exact in bf16) ----
    int rowLbl[4], slotLbl[4], colOk[4];
    {
        bf16x8 ones = splat8(1.f);
        bf16x8 lbl  = splat8((float)col);
        f32x4 pr = {0.f, 0.f, 0.f, 0.f};
        f32x4 pc = {0.f, 0.f, 0.f, 0.f};
        pr = __builtin_amdgcn_mfma_f32_16x16x32_bf16(lbl, ones, pr, 0, 0, 0);
        pc = __builtin_amdgcn_mfma_f32_16x16x32_bf16(ones, lbl, pc, 0, 0, 0);
        #pragma unroll
        for (int j = 0; j < 4; ++j) {
            rowLbl[j] = (int)(pr[j] * 0.03125f + 0.5f);
            int c     = (int)(pc[j] * 0.03125f + 0.5f);
            colOk[j]  = (c < 8);
            slotLbl[j] = 2 * (c & 3) + ((c >> 2) & 1);   // pair-interleaved slot
        }
    }

    bf16x8 B1h[2], B1l[2], B2h[2], B2l[2];
    build_b(G1, col, grp, B1h, B1l);
    build_b(G2, col, grp, B2h, B2l);

    float* T0 = &L[w][0][0];
    float* T1 = &L[w][1][0];
    float* T2 = &L[w][2][0];
    const int gw = blockIdx.x * 4 + w;

    #pragma unroll 1
    for (int it = 0; it < 4; ++it) {
        const int b = (it * NW + gw) * 64 + lane;
        float4 xv = make_float4(0.f, 0.f, 0.f, 0.f);
        if (b < B) xv = reinterpret_cast<const float4*>(X)[b];

        // ---- S1: t[r] = sum_d x0^d G0[d][r]; store pair-interleaved ----
        {
            float p[8];
            POWERS(p, xv.x)
            float t[8];
            #pragma unroll
            for (int r = 0; r < 8; ++r) {
                float a = 0.f;
                #pragma unroll
                for (int d = 0; d < 8; ++d)
                    a = fmaf(p[d], G0[d*8 + r], a);
                t[r] = a;
            }
            f32x4 v0 = {t[0], t[4], t[1], t[5]};
            f32x4 v1 = {t[2], t[6], t[3], t[7]};
            *reinterpret_cast<f32x4*>(&T0[lane*ROWW    ]) = v0;
            *reinterpret_cast<f32x4*>(&T0[lane*ROWW + 4]) = v1;
            *reinterpret_cast<float2*>(&T0[lane*ROWW + 8]) = make_float2(xv.y, xv.z);
        }
        wave_fence();

        // ---- S2 (MFMA): t1 = (t (x) P1) @ G1 ----
        #pragma unroll
        for (int g4 = 0; g4 < 4; ++g4) {
            const int base = (g4*16 + col) * ROWW;
            float2 tp = *reinterpret_cast<const float2*>(&T0[base + 2*grp]);
            float x1  = T0[base + 8];
            float p[8];
            POWERS(p, x1)
            float f0[8], f1[8];
            #pragma unroll
            for (int e = 0; e < 8; ++e) { f0[e] = tp.x*p[e]; f1[e] = tp.y*p[e]; }
            bf16x8 a0 = pack8(f0), a1 = pack8(f1);
            f32x4 acc = {0.f, 0.f, 0.f, 0.f};
            acc = __builtin_amdgcn_mfma_f32_16x16x32_bf16(a0, B1h[0], acc, 0, 0, 0);
            acc = __builtin_amdgcn_mfma_f32_16x16x32_bf16(a0, B1l[0], acc, 0, 0, 0);
            acc = __builtin_amdgcn_mfma_f32_16x16x32_bf16(a1, B1h[1], acc, 0, 0, 0);
            acc = __builtin_amdgcn_mfma_f32_16x16x32_bf16(a1, B1l[1], acc, 0, 0, 0);
            #pragma unroll
            for (int j = 0; j < 4; ++j)
                if (colOk[j])
                    T1[(g4*16 + rowLbl[j])*ROWW + slotLbl[j]] = acc[j];
        }
        wave_fence();

        // ---- S3 (MFMA): t2 = (t1 (x) P2) @ G2 ----
        #pragma unroll
        for (int g4 = 0; g4 < 4; ++g4) {
            const int base = (g4*16 + col) * ROWW;
            float2 tp = *reinterpret_cast<const float2*>(&T1[base + 2*grp]);
            float x2  = T0[base + 9];
            float p[8];
            POWERS(p, x2)
            float f0[8], f1[8];
            #pragma unroll
            for (int e = 0; e < 8; ++e) { f0[e] = tp.x*p[e]; f1[e] = tp.y*p[e]; }
            bf16x8 a0 = pack8(f0), a1 = pack8(f1);
            f32x4 acc = {0.f, 0.f, 0.f, 0.f};
            acc = __builtin_amdgcn_mfma_f32_16x16x32_bf16(a0, B2h[0], acc, 0, 0, 0);
            acc = __builtin_amdgcn_mfma_f32_16x16x32_bf16(a0, B2l[0], acc, 0, 0, 0);
            acc = __builtin_amdgcn_mfma_f32_16x16x32_bf16(a1, B2h[1], acc, 0, 0, 0);
            acc = __builtin_amdgcn_mfma_f32_16x16x32_bf16(a1, B2l[1], acc, 0, 0, 0);
            #pragma unroll
            for (int j = 0; j < 4; ++j)
                if (colOk[j])
                    T2[(g4*16 + rowLbl[j])*ROWW + slotLbl[j]] = acc[j];
        }
        wave_fence();

        // ---- S4: res = sum_t t2[t] * (G3[t]·P3); un-permute slots ----
        {
            f32x4 u0 = *reinterpret_cast<const f32x4*>(&T2[lane*ROWW    ]);
            f32x4 u1 = *reinterpret_cast<const f32x4*>(&T2[lane*ROWW + 4]);
            const int tmap[8] = {0, 4, 1, 5, 2, 6, 3, 7};   // slot -> t
            float p[8];
            POWERS(p, xv.w)
            float res = 0.f;
            #pragma unroll
            for (int sl = 0; sl < 8; ++sl) {
                const int t8 = tmap[sl];
                float wt = G3[t8*8];
                #pragma unroll
                for (int d = 1; d < 8; ++d)
                    wt = fmaf(p[d], G3[t8*8 + d], wt);
                float tv = (sl < 4) ? u0[sl] : u1[sl - 4];
                res = fmaf(tv, wt, res);
            }
            if (b < B) out[b] = res;
        }
    }
}

extern "C" void kernel_launch(void* const* d_in, const int* in_sizes, int n_in,
                              void* d_out, int out_size, void* d_ws, size_t ws_size,
                              hipStream_t stream) {
    const float* X  = (const float*)d_in[0];
    const float* G0 = (const float*)d_in[1];
    const float* G1 = (const float*)d_in[2];
    const float* G2 = (const float*)d_in[3];
    const float* G3 = (const float*)d_in[4];
    float* out = (float*)d_out;

    int B = in_sizes[0] / 4;                       // X is [B,4]
    int block = 256;
    int grid = (B + 1023) / 1024;                  // 1024 samples per block
    int NW = grid * 4;                             // total waves
    tt_poly_kernel<<<grid, block, 0, stream>>>(X, G0, G1, G2, G3, out, B, NW);
}